// Round 1
// baseline (616.367 us; speedup 1.0000x reference)
//
#include <hip/hip_runtime.h>
#include <cstdint>
#include <cstddef>

// DeformablePoseViT: bs=16, lq=1000, d=256, nh=8, L=4, P=4, dh=32
// value pyramid: (80,80),(40,40),(20,20),(10,10) -> lv=8500
//
// Pipeline:
//  1) gemm_bf16<true>  : vbf  = bf16(value @ W_val + b_val)          [136000x256]
//  2) gemm_bf16<false> : offl = query @ W_off + b_off                [16000x256]
//  3) gemm_bf16<false> : attnl= query @ W_attn + b_attn              [16000x128]
//  4) qpost            : softmax(attnl) -> attnw (in place), offl -> pixel locs
//  5) sample           : bilinear gather + attn-weighted sum -> outs (aliases offl)
//  6) gemm_bf16<false> : d_out = outs @ W_out + b_out                [16000x256]

typedef unsigned short u16;
typedef u16 u16x4 __attribute__((ext_vector_type(4)));
typedef u16 u16x8 __attribute__((ext_vector_type(8)));
typedef __bf16 bf16x8 __attribute__((ext_vector_type(8)));
typedef float f32x4 __attribute__((ext_vector_type(4)));

__device__ inline u16 f2bf(float f) {
  uint32_t u = __float_as_uint(f);
  u += 0x7fffu + ((u >> 16) & 1u);  // round-nearest-even
  return (u16)(u >> 16);
}
__device__ inline float bf2f(u16 v) {
  return __uint_as_float(((uint32_t)v) << 16);
}

// C[M,N] = A[M,K]f32 (cast bf16) @ B[K,N]f32 (cast bf16) + bias[N]
// BM=BN=128, BK=64, 256 threads = 4 waves in 2x2, wave tile 64x64 (4x4 frags)
template <bool OUT_BF16>
__global__ __launch_bounds__(256) void gemm_bf16(
    const float* __restrict__ A, const float* __restrict__ B,
    const float* __restrict__ bias, void* __restrict__ Cv,
    int M, int N, int K) {
  __shared__ __align__(16) u16 Asub[128 * 64];  // [row][k]
  __shared__ __align__(16) u16 Bsub[128 * 64];  // [col][k] (transposed)
  const int t = threadIdx.x;
  const int m0 = blockIdx.x * 128;
  const int n0 = blockIdx.y * 128;
  const int wave = t >> 6;
  const int lane = t & 63;
  const int wm = (wave >> 1) * 64;
  const int wn = (wave & 1) * 64;
  const int lr = lane & 15;
  const int kof = (lane >> 4) * 8;

  f32x4 acc[4][4] = {};

  for (int k0 = 0; k0 < K; k0 += 64) {
    // stage A tile 128x64 (row-major), f32 -> bf16
#pragma unroll
    for (int g = 0; g < 8; ++g) {
      int eidx = g * 1024 + t * 4;
      int row = eidx >> 6;
      int col = eidx & 63;
      float4 a4 = make_float4(0.f, 0.f, 0.f, 0.f);
      int gr = m0 + row;
      if (gr < M) a4 = *(const float4*)(A + (size_t)gr * K + k0 + col);
      u16x4 c4 = {f2bf(a4.x), f2bf(a4.y), f2bf(a4.z), f2bf(a4.w)};
      *(u16x4*)(Asub + row * 64 + col) = c4;
    }
    // stage B tile 64x128, transposed into Bsub[col][k]
#pragma unroll
    for (int g = 0; g < 8; ++g) {
      int idx = g * 256 + t;
      int col = idx & 127;
      int k4 = (idx >> 7) * 4;
      const float* bp = B + (size_t)(k0 + k4) * N + n0 + col;
      u16x4 c4 = {f2bf(bp[0]), f2bf(bp[(size_t)N]), f2bf(bp[(size_t)2 * N]),
                  f2bf(bp[(size_t)3 * N])};
      *(u16x4*)(Bsub + col * 64 + k4) = c4;
    }
    __syncthreads();
#pragma unroll
    for (int kk = 0; kk < 64; kk += 32) {
      bf16x8 af[4], bfr[4];
#pragma unroll
      for (int mi = 0; mi < 4; ++mi)
        af[mi] = __builtin_bit_cast(
            bf16x8, *(const u16x8*)(Asub + (wm + mi * 16 + lr) * 64 + kk + kof));
#pragma unroll
      for (int ni = 0; ni < 4; ++ni)
        bfr[ni] = __builtin_bit_cast(
            bf16x8, *(const u16x8*)(Bsub + (wn + ni * 16 + lr) * 64 + kk + kof));
#pragma unroll
      for (int mi = 0; mi < 4; ++mi)
#pragma unroll
        for (int ni = 0; ni < 4; ++ni)
          acc[mi][ni] = __builtin_amdgcn_mfma_f32_16x16x32_bf16(
              af[mi], bfr[ni], acc[mi][ni], 0, 0, 0);
    }
    __syncthreads();
  }

  // epilogue: C layout col=lane&15, row=(lane>>4)*4+r
  float bv[4];
#pragma unroll
  for (int ni = 0; ni < 4; ++ni) bv[ni] = bias[n0 + wn + ni * 16 + lr];
  const int rit = (lane >> 4) * 4;
#pragma unroll
  for (int mi = 0; mi < 4; ++mi) {
#pragma unroll
    for (int r = 0; r < 4; ++r) {
      int grow = m0 + wm + mi * 16 + rit + r;
      if (grow >= M) continue;
#pragma unroll
      for (int ni = 0; ni < 4; ++ni) {
        int gcol = n0 + wn + ni * 16 + lr;
        float v = acc[mi][ni][r] + bv[ni];
        if (OUT_BF16)
          ((u16*)Cv)[(size_t)grow * N + gcol] = f2bf(v);
        else
          ((float*)Cv)[(size_t)grow * N + gcol] = v;
      }
    }
  }
}

// softmax over L*P=16 per head + pixel-space sampling locations
// block = one query (i in [0,16000)), 256 threads
__global__ __launch_bounds__(256) void qpost(
    const float* __restrict__ offl, const float* __restrict__ attnl,
    const float* __restrict__ bbox, float* __restrict__ locs,
    float* __restrict__ attnw) {
  const int i = blockIdx.x;
  const int t = threadIdx.x;
  __shared__ float sal[128];
  if (t < 128) sal[t] = attnl[(size_t)i * 128 + t];
  __syncthreads();
  if (t < 128) {
    int h = t >> 4;
    float mx = -3.0e38f;
#pragma unroll
    for (int j = 0; j < 16; ++j) mx = fmaxf(mx, sal[h * 16 + j]);
    float sum = 0.f;
#pragma unroll
    for (int j = 0; j < 16; ++j) sum += __expf(sal[h * 16 + j] - mx);
    attnw[(size_t)i * 128 + t] = __expf(sal[t] - mx) / sum;
  }
  // location: t = h*32 + l*8 + p*2 + xy
  int r = t & 31;
  int l = r >> 3;
  int xy = r & 1;
  float off = offl[(size_t)i * 256 + t];
  float c = bbox[(size_t)i * 4 + xy];
  float wh = bbox[(size_t)i * 4 + 2 + xy];
  float loc = c + off * 0.125f * wh;  // off/P * wh * 0.5
  float size = (float)(80 >> l);      // 80,40,20,10 (square levels)
  locs[(size_t)i * 256 + t] = loc * size - 0.5f;
}

// bilinear sampling + attention-weighted accumulate
// block = one query, 256 threads = 8 heads x 32 channels
__global__ __launch_bounds__(256) void sample(
    const float* __restrict__ locs, const float* __restrict__ attnw,
    const u16* __restrict__ vbf, float* __restrict__ outs) {
  const int i = blockIdx.x;
  const int b = i / 1000;
  const int t = threadIdx.x;
  __shared__ float sl[256];
  __shared__ float sa[128];
  sl[t] = locs[(size_t)i * 256 + t];
  if (t < 128) sa[t] = attnw[(size_t)i * 128 + t];
  __syncthreads();
  const int h = t >> 5;
  const u16* vb = vbf + (size_t)b * 8500 * 256;
  float acc = 0.f;
  const int baseL[4] = {0, 6400, 8000, 8400};
  const int dimL[4] = {80, 40, 20, 10};
#pragma unroll
  for (int l = 0; l < 4; ++l) {
    const int W = dimL[l];
    const u16* vl = vb + (size_t)baseL[l] * 256;
#pragma unroll
    for (int p = 0; p < 4; ++p) {
      float x = sl[h * 32 + l * 8 + p * 2 + 0];
      float y = sl[h * 32 + l * 8 + p * 2 + 1];
      float aw = sa[h * 16 + l * 4 + p];
      float x0f = floorf(x), y0f = floorf(y);
      float wx = x - x0f, wy = y - y0f;
      int x0 = (int)x0f, y0 = (int)y0f;
      int x1 = x0 + 1, y1 = y0 + 1;
      bool vx0 = (x0 >= 0) & (x0 < W), vx1 = (x1 >= 0) & (x1 < W);
      bool vy0 = (y0 >= 0) & (y0 < W), vy1 = (y1 >= 0) & (y1 < W);
      int xc0 = min(max(x0, 0), W - 1), xc1 = min(max(x1, 0), W - 1);
      int yc0 = min(max(y0, 0), W - 1), yc1 = min(max(y1, 0), W - 1);
      float v00 = (vx0 & vy0) ? bf2f(vl[((size_t)(yc0 * W + xc0)) * 256 + t]) : 0.f;
      float v01 = (vx1 & vy0) ? bf2f(vl[((size_t)(yc0 * W + xc1)) * 256 + t]) : 0.f;
      float v10 = (vx0 & vy1) ? bf2f(vl[((size_t)(yc1 * W + xc0)) * 256 + t]) : 0.f;
      float v11 = (vx1 & vy1) ? bf2f(vl[((size_t)(yc1 * W + xc1)) * 256 + t]) : 0.f;
      float s = v00 * (1.f - wx) * (1.f - wy) + v01 * wx * (1.f - wy) +
                v10 * (1.f - wx) * wy + v11 * wx * wy;
      acc += aw * s;
    }
  }
  outs[(size_t)i * 256 + t] = acc;
}

extern "C" void kernel_launch(void* const* d_in, const int* in_sizes, int n_in,
                              void* d_out, int out_size, void* d_ws, size_t ws_size,
                              hipStream_t stream) {
  const float* query  = (const float*)d_in[0];
  const float* bbox   = (const float*)d_in[1];
  const float* value  = (const float*)d_in[2];
  const float* W_off  = (const float*)d_in[3];
  const float* b_off  = (const float*)d_in[4];
  const float* W_attn = (const float*)d_in[5];
  const float* b_attn = (const float*)d_in[6];
  const float* W_val  = (const float*)d_in[7];
  const float* b_val  = (const float*)d_in[8];
  const float* W_out  = (const float*)d_in[9];
  const float* b_out  = (const float*)d_in[10];
  float* out = (float*)d_out;

  // workspace layout
  char* w = (char*)d_ws;
  u16* vbf    = (u16*)w;                              // 136000*256*2 = 69,632,000 B
  float* offl = (float*)(w + 69632000);               // 16000*256*4  = 16,384,000 B (reused as outs)
  float* attnl= (float*)(w + 69632000 + 16384000);    // 16000*128*4  =  8,192,000 B (reused as attnw)
  float* locs = (float*)(w + 69632000 + 16384000 + 8192000);  // 16,384,000 B
  float* outs = offl;   // alias: offl consumed by qpost before sample writes
  float* attnw = attnl; // alias: in-place softmax (block-local)

  const int M_v = 16 * 8500;  // 136000
  const int M_q = 16 * 1000;  // 16000

  // 1) value projection -> bf16
  gemm_bf16<true><<<dim3((M_v + 127) / 128, 2), 256, 0, stream>>>(
      value, W_val, b_val, (void*)vbf, M_v, 256, 256);
  // 2) offset logits
  gemm_bf16<false><<<dim3(M_q / 128, 2), 256, 0, stream>>>(
      query, W_off, b_off, (void*)offl, M_q, 256, 256);
  // 3) attn logits
  gemm_bf16<false><<<dim3(M_q / 128, 1), 256, 0, stream>>>(
      query, W_attn, b_attn, (void*)attnl, M_q, 128, 256);
  // 4) softmax + locations
  qpost<<<M_q, 256, 0, stream>>>(offl, attnl, bbox, locs, attnw);
  // 5) bilinear sampling (writes outs == offl)
  sample<<<M_q, 256, 0, stream>>>(locs, attnw, vbf, outs);
  // 6) output projection
  gemm_bf16<false><<<dim3(M_q / 128, 2), 256, 0, stream>>>(
      outs, W_out, b_out, (void*)out, M_q, 256, 256);
}

// Round 2
// 289.889 us; speedup vs baseline: 2.1262x; 2.1262x over previous
//
#include <hip/hip_runtime.h>
#include <cstdint>
#include <cstddef>

// DeformablePoseViT: bs=16, lq=1000, d=256, nh=8, L=4, P=4, dh=32
// value pyramid: (80,80),(40,40),(20,20),(10,10) -> lv=8500
//
// Pipeline:
//  1) gemm_bf16<true>  : vbf  = bf16(value @ W_val + b_val)          [136000x256]
//  2) gemm_bf16<false> : offl = query @ W_off + b_off                [16000x256]
//  3) gemm_bf16<false> : attnl= query @ W_attn + b_attn              [16000x128]
//  4) qpost            : softmax(attnl) -> attnw (in place), offl -> pixel locs
//  5) sample           : bilinear gather + attn-weighted sum -> outs (aliases offl)
//  6) gemm_bf16<false> : d_out = outs @ W_out + b_out                [16000x256]

typedef unsigned short u16;
typedef u16 u16x4 __attribute__((ext_vector_type(4)));
typedef u16 u16x8 __attribute__((ext_vector_type(8)));
typedef __bf16 bf16x8 __attribute__((ext_vector_type(8)));
typedef float f32x4 __attribute__((ext_vector_type(4)));

__device__ inline u16 f2bf(float f) {
  uint32_t u = __float_as_uint(f);
  u += 0x7fffu + ((u >> 16) & 1u);  // round-nearest-even
  return (u16)(u >> 16);
}

// C[M,N] = A[M,K]f32 (cast bf16) @ B[K,N]f32 (cast bf16) + bias[N]
// BM=BN=128, BK=64, 256 threads = 4 waves in 2x2, wave tile 64x64 (4x4 frags)
template <bool OUT_BF16>
__global__ __launch_bounds__(256) void gemm_bf16(
    const float* __restrict__ A, const float* __restrict__ B,
    const float* __restrict__ bias, void* __restrict__ Cv,
    int M, int N, int K) {
  __shared__ __align__(16) u16 Asub[128 * 64];  // [row][k]
  __shared__ __align__(16) u16 Bsub[128 * 64];  // [col][k] (transposed)
  const int t = threadIdx.x;
  const int m0 = blockIdx.x * 128;
  const int n0 = blockIdx.y * 128;
  const int wave = t >> 6;
  const int lane = t & 63;
  const int wm = (wave >> 1) * 64;
  const int wn = (wave & 1) * 64;
  const int lr = lane & 15;
  const int kof = (lane >> 4) * 8;

  f32x4 acc[4][4] = {};

  for (int k0 = 0; k0 < K; k0 += 64) {
    // stage A tile 128x64 (row-major), f32 -> bf16
#pragma unroll
    for (int g = 0; g < 8; ++g) {
      int eidx = g * 1024 + t * 4;
      int row = eidx >> 6;
      int col = eidx & 63;
      float4 a4 = make_float4(0.f, 0.f, 0.f, 0.f);
      int gr = m0 + row;
      if (gr < M) a4 = *(const float4*)(A + (size_t)gr * K + k0 + col);
      u16x4 c4 = {f2bf(a4.x), f2bf(a4.y), f2bf(a4.z), f2bf(a4.w)};
      *(u16x4*)(Asub + row * 64 + col) = c4;
    }
    // stage B tile 64x128, transposed into Bsub[col][k]
#pragma unroll
    for (int g = 0; g < 8; ++g) {
      int idx = g * 256 + t;
      int col = idx & 127;
      int k4 = (idx >> 7) * 4;
      const float* bp = B + (size_t)(k0 + k4) * N + n0 + col;
      u16x4 c4 = {f2bf(bp[0]), f2bf(bp[(size_t)N]), f2bf(bp[(size_t)2 * N]),
                  f2bf(bp[(size_t)3 * N])};
      *(u16x4*)(Bsub + col * 64 + k4) = c4;
    }
    __syncthreads();
#pragma unroll
    for (int kk = 0; kk < 64; kk += 32) {
      bf16x8 af[4], bfr[4];
#pragma unroll
      for (int mi = 0; mi < 4; ++mi)
        af[mi] = __builtin_bit_cast(
            bf16x8, *(const u16x8*)(Asub + (wm + mi * 16 + lr) * 64 + kk + kof));
#pragma unroll
      for (int ni = 0; ni < 4; ++ni)
        bfr[ni] = __builtin_bit_cast(
            bf16x8, *(const u16x8*)(Bsub + (wn + ni * 16 + lr) * 64 + kk + kof));
#pragma unroll
      for (int mi = 0; mi < 4; ++mi)
#pragma unroll
        for (int ni = 0; ni < 4; ++ni)
          acc[mi][ni] = __builtin_amdgcn_mfma_f32_16x16x32_bf16(
              af[mi], bfr[ni], acc[mi][ni], 0, 0, 0);
    }
    __syncthreads();
  }

  // epilogue: C layout col=lane&15, row=(lane>>4)*4+r
  float bv[4];
#pragma unroll
  for (int ni = 0; ni < 4; ++ni) bv[ni] = bias[n0 + wn + ni * 16 + lr];
  const int rit = (lane >> 4) * 4;
#pragma unroll
  for (int mi = 0; mi < 4; ++mi) {
#pragma unroll
    for (int r = 0; r < 4; ++r) {
      int grow = m0 + wm + mi * 16 + rit + r;
      if (grow >= M) continue;
#pragma unroll
      for (int ni = 0; ni < 4; ++ni) {
        int gcol = n0 + wn + ni * 16 + lr;
        float v = acc[mi][ni][r] + bv[ni];
        if (OUT_BF16)
          ((u16*)Cv)[(size_t)grow * N + gcol] = f2bf(v);
        else
          ((float*)Cv)[(size_t)grow * N + gcol] = v;
      }
    }
  }
}

// softmax over L*P=16 per head + pixel-space sampling locations
// block = one query (i in [0,16000)), 256 threads
__global__ __launch_bounds__(256) void qpost(
    const float* __restrict__ offl, const float* __restrict__ attnl,
    const float* __restrict__ bbox, float* __restrict__ locs,
    float* __restrict__ attnw) {
  const int i = blockIdx.x;
  const int t = threadIdx.x;
  __shared__ float sal[128];
  if (t < 128) sal[t] = attnl[(size_t)i * 128 + t];
  __syncthreads();
  if (t < 128) {
    int h = t >> 4;
    float mx = -3.0e38f;
#pragma unroll
    for (int j = 0; j < 16; ++j) mx = fmaxf(mx, sal[h * 16 + j]);
    float sum = 0.f;
#pragma unroll
    for (int j = 0; j < 16; ++j) sum += __expf(sal[h * 16 + j] - mx);
    attnw[(size_t)i * 128 + t] = __expf(sal[t] - mx) / sum;
  }
  // location: t = h*32 + l*8 + p*2 + xy
  int r = t & 31;
  int l = r >> 3;
  int xy = r & 1;
  float off = offl[(size_t)i * 256 + t];
  float c = bbox[(size_t)i * 4 + xy];
  float wh = bbox[(size_t)i * 4 + 2 + xy];
  float loc = c + off * 0.125f * wh;  // off/P * wh * 0.5
  float size = (float)(80 >> l);      // 80,40,20,10 (square levels)
  locs[(size_t)i * 256 + t] = loc * size - 0.5f;
}

// ---------------------------------------------------------------------------
// bilinear sampling + attention-weighted accumulate, wide-load version.
// 8 queries per block. 256 threads: t = ql*32 + r; ql = query-in-block (0..7),
// r = h*4 + cg  (h = head 0..7, cg = 8-channel group 0..3).
// Each thread: for 16 points, 4 corners, one 16B (8x bf16) load -> 8-ch acc.
__global__ __launch_bounds__(256) void sample(
    const float* __restrict__ locs, const float* __restrict__ attnw,
    const u16* __restrict__ vbf, float* __restrict__ outs) {
  const int blk = blockIdx.x;
  const int i0 = blk * 8;
  const int t = threadIdx.x;
  __shared__ __align__(16) float sl[8 * 256];
  __shared__ __align__(16) float sa[8 * 128];
  {
    const float4* src = (const float4*)(locs + (size_t)i0 * 256);
    float4* dst = (float4*)sl;
    dst[t] = src[t];
    dst[t + 256] = src[t + 256];
    ((float4*)sa)[t] = ((const float4*)(attnw + (size_t)i0 * 128))[t];
  }
  __syncthreads();
  const int ql = t >> 5;
  const int r = t & 31;
  const int h = r >> 2;
  const int cg = r & 3;
  const int choff = h * 32 + cg * 8;  // u16 elements; 16B aligned
  const int i = i0 + ql;
  const int b = blk / 125;  // 125 blocks per batch (1000 q / 8)
  const u16* vb = vbf + (size_t)b * 8500 * 256;

  float acc[8] = {};
  const int baseL[4] = {0, 6400, 8000, 8400};
  const int dimL[4] = {80, 40, 20, 10};

#pragma unroll
  for (int l = 0; l < 4; ++l) {
    const int W = dimL[l];
    const u16* vl = vb + (size_t)baseL[l] * 256 + choff;
#pragma unroll
    for (int p = 0; p < 4; ++p) {
      float x = sl[ql * 256 + h * 32 + l * 8 + p * 2 + 0];
      float y = sl[ql * 256 + h * 32 + l * 8 + p * 2 + 1];
      float aw = sa[ql * 128 + h * 16 + l * 4 + p];
      float x0f = floorf(x), y0f = floorf(y);
      float wx = x - x0f, wy = y - y0f;
      int x0 = (int)x0f, y0 = (int)y0f;
      int x1 = x0 + 1, y1 = y0 + 1;
      float fx0 = (x0 >= 0 && x0 < W) ? 1.f : 0.f;
      float fx1 = (x1 >= 0 && x1 < W) ? 1.f : 0.f;
      float fy0 = (y0 >= 0 && y0 < W) ? 1.f : 0.f;
      float fy1 = (y1 >= 0 && y1 < W) ? 1.f : 0.f;
      int xc0 = min(max(x0, 0), W - 1), xc1 = min(max(x1, 0), W - 1);
      int yc0 = min(max(y0, 0), W - 1), yc1 = min(max(y1, 0), W - 1);
      // fold attn weight + validity into per-corner scalar weights
      float w00 = aw * (1.f - wx) * (1.f - wy) * fx0 * fy0;
      float w01 = aw * wx * (1.f - wy) * fx1 * fy0;
      float w10 = aw * (1.f - wx) * wy * fx0 * fy1;
      float w11 = aw * wx * wy * fx1 * fy1;
      uint4 v00 = *(const uint4*)(vl + (size_t)(yc0 * W + xc0) * 256);
      uint4 v01 = *(const uint4*)(vl + (size_t)(yc0 * W + xc1) * 256);
      uint4 v10 = *(const uint4*)(vl + (size_t)(yc1 * W + xc0) * 256);
      uint4 v11 = *(const uint4*)(vl + (size_t)(yc1 * W + xc1) * 256);
      const uint32_t* p00 = (const uint32_t*)&v00;
      const uint32_t* p01 = (const uint32_t*)&v01;
      const uint32_t* p10 = (const uint32_t*)&v10;
      const uint32_t* p11 = (const uint32_t*)&v11;
#pragma unroll
      for (int k = 0; k < 4; ++k) {
        float a0 = __uint_as_float(p00[k] << 16);
        float a1 = __uint_as_float(p00[k] & 0xffff0000u);
        float b0 = __uint_as_float(p01[k] << 16);
        float b1 = __uint_as_float(p01[k] & 0xffff0000u);
        float c0 = __uint_as_float(p10[k] << 16);
        float c1 = __uint_as_float(p10[k] & 0xffff0000u);
        float d0 = __uint_as_float(p11[k] << 16);
        float d1 = __uint_as_float(p11[k] & 0xffff0000u);
        acc[2 * k] += w00 * a0 + w01 * b0 + w10 * c0 + w11 * d0;
        acc[2 * k + 1] += w00 * a1 + w01 * b1 + w10 * c1 + w11 * d1;
      }
    }
  }
  float4* op = (float4*)(outs + (size_t)i * 256 + choff);
  op[0] = make_float4(acc[0], acc[1], acc[2], acc[3]);
  op[1] = make_float4(acc[4], acc[5], acc[6], acc[7]);
}

extern "C" void kernel_launch(void* const* d_in, const int* in_sizes, int n_in,
                              void* d_out, int out_size, void* d_ws, size_t ws_size,
                              hipStream_t stream) {
  const float* query  = (const float*)d_in[0];
  const float* bbox   = (const float*)d_in[1];
  const float* value  = (const float*)d_in[2];
  const float* W_off  = (const float*)d_in[3];
  const float* b_off  = (const float*)d_in[4];
  const float* W_attn = (const float*)d_in[5];
  const float* b_attn = (const float*)d_in[6];
  const float* W_val  = (const float*)d_in[7];
  const float* b_val  = (const float*)d_in[8];
  const float* W_out  = (const float*)d_in[9];
  const float* b_out  = (const float*)d_in[10];
  float* out = (float*)d_out;

  // workspace layout
  char* w = (char*)d_ws;
  u16* vbf    = (u16*)w;                              // 136000*256*2 = 69,632,000 B
  float* offl = (float*)(w + 69632000);               // 16000*256*4  = 16,384,000 B (reused as outs)
  float* attnl= (float*)(w + 69632000 + 16384000);    // 16000*128*4  =  8,192,000 B (reused as attnw)
  float* locs = (float*)(w + 69632000 + 16384000 + 8192000);  // 16,384,000 B
  float* outs = offl;   // alias: offl consumed by qpost before sample writes
  float* attnw = attnl; // alias: in-place softmax (block-local)

  const int M_v = 16 * 8500;  // 136000
  const int M_q = 16 * 1000;  // 16000

  // 1) value projection -> bf16
  gemm_bf16<true><<<dim3((M_v + 127) / 128, 2), 256, 0, stream>>>(
      value, W_val, b_val, (void*)vbf, M_v, 256, 256);
  // 2) offset logits
  gemm_bf16<false><<<dim3(M_q / 128, 2), 256, 0, stream>>>(
      query, W_off, b_off, (void*)offl, M_q, 256, 256);
  // 3) attn logits
  gemm_bf16<false><<<dim3(M_q / 128, 1), 256, 0, stream>>>(
      query, W_attn, b_attn, (void*)attnl, M_q, 128, 256);
  // 4) softmax + locations
  qpost<<<M_q, 256, 0, stream>>>(offl, attnl, bbox, locs, attnw);
  // 5) bilinear sampling (writes outs == offl)
  sample<<<2000, 256, 0, stream>>>(locs, attnw, vbf, outs);
  // 6) output projection
  gemm_bf16<false><<<dim3(M_q / 128, 2), 256, 0, stream>>>(
      outs, W_out, b_out, (void*)out, M_q, 256, 256);
}

// Round 3
// 244.401 us; speedup vs baseline: 2.5220x; 1.1861x over previous
//
#include <hip/hip_runtime.h>
#include <cstdint>
#include <cstddef>

// DeformablePoseViT: bs=16, lq=1000, d=256, nh=8, L=4, P=4, dh=32
// value pyramid: (80,80),(40,40),(20,20),(10,10) -> lv=8500
//
// Pipeline:
//  0) wconv            : Wt_* = bf16(W_*^T)  [N][K=256] for all 4 weights
//  1) gemm_bf16<true>  : vbf  = bf16(value @ W_val + b_val)          [136000x256]
//  2) gemm_bf16<false> : offl = query @ W_off + b_off                [16000x256]
//  3) gemm_bf16<false> : attnl= query @ W_attn + b_attn              [16000x128]
//  4) qpost            : softmax(attnl) -> attnw, offl -> pixel locs
//  5) sample           : bilinear gather + attn-weighted sum -> outs
//  6) gemm_bf16<false> : d_out = outs @ W_out + b_out                [16000x256]

typedef unsigned short u16;
typedef u16 u16x4 __attribute__((ext_vector_type(4)));
typedef u16 u16x8 __attribute__((ext_vector_type(8)));
typedef __bf16 bf16x8 __attribute__((ext_vector_type(8)));
typedef float f32x4 __attribute__((ext_vector_type(4)));

__device__ inline u16 f2bf(float f) {
  return __builtin_bit_cast(u16, (__bf16)f);
}

// ---------------------------------------------------------------------------
// Weight prep: Wt[n][k] = bf16(W[k][n]) for the 4 weight matrices. K=256 all.
// grid (4,4,4): x->n-tile, y->k-tile, z->matrix. 64x64 tiles via LDS.
__global__ __launch_bounds__(256) void wconv(
    const float* __restrict__ W0, const float* __restrict__ W1,
    const float* __restrict__ W2, const float* __restrict__ W3,
    u16* __restrict__ T0, u16* __restrict__ T1, u16* __restrict__ T2,
    u16* __restrict__ T3) {
  __shared__ u16 tile[64][65];
  const float* Ws[4] = {W0, W1, W2, W3};
  u16* Ts[4] = {T0, T1, T2, T3};
  const int Ns[4] = {256, 256, 128, 256};
  const int z = blockIdx.z;
  const int N = Ns[z];
  const int n0 = blockIdx.x * 64;
  if (n0 >= N) return;
  const int k0 = blockIdx.y * 64;
  const float* W = Ws[z];
  u16* Wt = Ts[z];
  const int tr = threadIdx.x >> 6;   // 0..3
  const int tc = threadIdx.x & 63;
#pragma unroll
  for (int r = 0; r < 64; r += 4)
    tile[r + tr][tc] = f2bf(W[(size_t)(k0 + r + tr) * N + n0 + tc]);
  __syncthreads();
#pragma unroll
  for (int r = 0; r < 64; r += 4)
    Wt[(size_t)(n0 + r + tr) * 256 + k0 + tc] = tile[tc][r + tr];
}

// ---------------------------------------------------------------------------
// C[M,N] = A[M,256]f32 (cast bf16) @ Wt[N,256]bf16^T + bias[N]
// BM=BN=128, BK=64, 256 threads = 4 waves 2x2, wave tile 64x64 (4x4 frags).
// LDS tiles XOR-swizzled: byte ^= (row&7)<<4 (st-16x32 style).
template <bool OUT_BF16>
__global__ __launch_bounds__(256) void gemm_bf16(
    const float* __restrict__ A, const u16* __restrict__ Wt,
    const float* __restrict__ bias, void* __restrict__ Cv, int M, int N) {
  __shared__ __align__(16) u16 Asub[128 * 64];  // [row][k], swizzled
  __shared__ __align__(16) u16 Bsub[128 * 64];  // [col][k], swizzled
  const int t = threadIdx.x;
  const int m0 = blockIdx.x * 128;
  const int n0 = blockIdx.y * 128;
  const int wave = t >> 6;
  const int lane = t & 63;
  const int wm = (wave >> 1) * 64;
  const int wn = (wave & 1) * 64;
  const int lr = lane & 15;
  const int kof = (lane >> 4) * 8;

  f32x4 acc[4][4] = {};

#pragma unroll
  for (int k0 = 0; k0 < 256; k0 += 64) {
    // stage A tile 128x64 (f32 -> bf16), swizzled LDS writes
#pragma unroll
    for (int g = 0; g < 8; ++g) {
      int eidx = g * 1024 + t * 4;
      int row = eidx >> 6;
      int col = eidx & 63;
      float4 a4 = make_float4(0.f, 0.f, 0.f, 0.f);
      int gr = m0 + row;
      if (gr < M) a4 = *(const float4*)(A + (size_t)gr * 256 + k0 + col);
      u16x4 c4 = {f2bf(a4.x), f2bf(a4.y), f2bf(a4.z), f2bf(a4.w)};
      int byteoff = row * 128 + ((col * 2) ^ ((row & 7) << 4));
      *(u16x4*)((char*)Asub + byteoff) = c4;
    }
    // stage B tile 128 cols x 64 k from Wt (bf16, coalesced 16B loads)
#pragma unroll
    for (int g = 0; g < 4; ++g) {
      int chunk = g * 256 + t;   // 1024 x 16B
      int col = chunk >> 3;
      int kc = chunk & 7;
      u16x8 v = *(const u16x8*)(Wt + (size_t)(n0 + col) * 256 + k0 + kc * 8);
      int byteoff = col * 128 + ((kc * 16) ^ ((col & 7) << 4));
      *(u16x8*)((char*)Bsub + byteoff) = v;
    }
    __syncthreads();
#pragma unroll
    for (int kk = 0; kk < 64; kk += 32) {
      bf16x8 af[4], bfr[4];
#pragma unroll
      for (int mi = 0; mi < 4; ++mi) {
        int row = wm + mi * 16 + lr;
        int byteoff = row * 128 + (((kk + kof) * 2) ^ ((row & 7) << 4));
        af[mi] = __builtin_bit_cast(bf16x8, *(const u16x8*)((char*)Asub + byteoff));
      }
#pragma unroll
      for (int ni = 0; ni < 4; ++ni) {
        int row = wn + ni * 16 + lr;
        int byteoff = row * 128 + (((kk + kof) * 2) ^ ((row & 7) << 4));
        bfr[ni] = __builtin_bit_cast(bf16x8, *(const u16x8*)((char*)Bsub + byteoff));
      }
#pragma unroll
      for (int mi = 0; mi < 4; ++mi)
#pragma unroll
        for (int ni = 0; ni < 4; ++ni)
          acc[mi][ni] = __builtin_amdgcn_mfma_f32_16x16x32_bf16(
              af[mi], bfr[ni], acc[mi][ni], 0, 0, 0);
    }
    __syncthreads();
  }

  // epilogue: C layout col=lane&15, row=(lane>>4)*4+r
  float bv[4];
#pragma unroll
  for (int ni = 0; ni < 4; ++ni) bv[ni] = bias[n0 + wn + ni * 16 + lr];
  const int rit = (lane >> 4) * 4;
#pragma unroll
  for (int mi = 0; mi < 4; ++mi) {
#pragma unroll
    for (int r = 0; r < 4; ++r) {
      int grow = m0 + wm + mi * 16 + rit + r;
      if (grow >= M) continue;
#pragma unroll
      for (int ni = 0; ni < 4; ++ni) {
        int gcol = n0 + wn + ni * 16 + lr;
        float v = acc[mi][ni][r] + bv[ni];
        if (OUT_BF16)
          ((u16*)Cv)[(size_t)grow * N + gcol] = f2bf(v);
        else
          ((float*)Cv)[(size_t)grow * N + gcol] = v;
      }
    }
  }
}

// softmax over L*P=16 per head + pixel-space sampling locations
__global__ __launch_bounds__(256) void qpost(
    const float* __restrict__ offl, const float* __restrict__ attnl,
    const float* __restrict__ bbox, float* __restrict__ locs,
    float* __restrict__ attnw) {
  const int i = blockIdx.x;
  const int t = threadIdx.x;
  __shared__ float sal[128];
  if (t < 128) sal[t] = attnl[(size_t)i * 128 + t];
  __syncthreads();
  if (t < 128) {
    int h = t >> 4;
    float mx = -3.0e38f;
#pragma unroll
    for (int j = 0; j < 16; ++j) mx = fmaxf(mx, sal[h * 16 + j]);
    float sum = 0.f;
#pragma unroll
    for (int j = 0; j < 16; ++j) sum += __expf(sal[h * 16 + j] - mx);
    attnw[(size_t)i * 128 + t] = __expf(sal[t] - mx) / sum;
  }
  int r = t & 31;
  int l = r >> 3;
  int xy = r & 1;
  float off = offl[(size_t)i * 256 + t];
  float c = bbox[(size_t)i * 4 + xy];
  float wh = bbox[(size_t)i * 4 + 2 + xy];
  float loc = c + off * 0.125f * wh;  // off/P * wh * 0.5
  float size = (float)(80 >> l);      // 80,40,20,10
  locs[(size_t)i * 256 + t] = loc * size - 0.5f;
}

// ---------------------------------------------------------------------------
// bilinear sampling: 8 queries/block, 256 threads = ql*32 + (h*4 + cg)
__global__ __launch_bounds__(256) void sample(
    const float* __restrict__ locs, const float* __restrict__ attnw,
    const u16* __restrict__ vbf, float* __restrict__ outs) {
  const int blk = blockIdx.x;
  const int i0 = blk * 8;
  const int t = threadIdx.x;
  __shared__ __align__(16) float sl[8 * 256];
  __shared__ __align__(16) float sa[8 * 128];
  {
    const float4* src = (const float4*)(locs + (size_t)i0 * 256);
    float4* dst = (float4*)sl;
    dst[t] = src[t];
    dst[t + 256] = src[t + 256];
    ((float4*)sa)[t] = ((const float4*)(attnw + (size_t)i0 * 128))[t];
  }
  __syncthreads();
  const int ql = t >> 5;
  const int r = t & 31;
  const int h = r >> 2;
  const int cg = r & 3;
  const int choff = h * 32 + cg * 8;
  const int i = i0 + ql;
  const int b = blk / 125;
  const u16* vb = vbf + (size_t)b * 8500 * 256;

  float acc[8] = {};
  const int baseL[4] = {0, 6400, 8000, 8400};
  const int dimL[4] = {80, 40, 20, 10};

#pragma unroll
  for (int l = 0; l < 4; ++l) {
    const int W = dimL[l];
    const u16* vl = vb + (size_t)baseL[l] * 256 + choff;
#pragma unroll
    for (int p = 0; p < 4; ++p) {
      float x = sl[ql * 256 + h * 32 + l * 8 + p * 2 + 0];
      float y = sl[ql * 256 + h * 32 + l * 8 + p * 2 + 1];
      float aw = sa[ql * 128 + h * 16 + l * 4 + p];
      float x0f = floorf(x), y0f = floorf(y);
      float wx = x - x0f, wy = y - y0f;
      int x0 = (int)x0f, y0 = (int)y0f;
      int x1 = x0 + 1, y1 = y0 + 1;
      float fx0 = (x0 >= 0 && x0 < W) ? 1.f : 0.f;
      float fx1 = (x1 >= 0 && x1 < W) ? 1.f : 0.f;
      float fy0 = (y0 >= 0 && y0 < W) ? 1.f : 0.f;
      float fy1 = (y1 >= 0 && y1 < W) ? 1.f : 0.f;
      int xc0 = min(max(x0, 0), W - 1), xc1 = min(max(x1, 0), W - 1);
      int yc0 = min(max(y0, 0), W - 1), yc1 = min(max(y1, 0), W - 1);
      float w00 = aw * (1.f - wx) * (1.f - wy) * fx0 * fy0;
      float w01 = aw * wx * (1.f - wy) * fx1 * fy0;
      float w10 = aw * (1.f - wx) * wy * fx0 * fy1;
      float w11 = aw * wx * wy * fx1 * fy1;
      uint4 v00 = *(const uint4*)(vl + (size_t)(yc0 * W + xc0) * 256);
      uint4 v01 = *(const uint4*)(vl + (size_t)(yc0 * W + xc1) * 256);
      uint4 v10 = *(const uint4*)(vl + (size_t)(yc1 * W + xc0) * 256);
      uint4 v11 = *(const uint4*)(vl + (size_t)(yc1 * W + xc1) * 256);
      const uint32_t* p00 = (const uint32_t*)&v00;
      const uint32_t* p01 = (const uint32_t*)&v01;
      const uint32_t* p10 = (const uint32_t*)&v10;
      const uint32_t* p11 = (const uint32_t*)&v11;
#pragma unroll
      for (int k = 0; k < 4; ++k) {
        float a0 = __uint_as_float(p00[k] << 16);
        float a1 = __uint_as_float(p00[k] & 0xffff0000u);
        float b0 = __uint_as_float(p01[k] << 16);
        float b1 = __uint_as_float(p01[k] & 0xffff0000u);
        float c0 = __uint_as_float(p10[k] << 16);
        float c1 = __uint_as_float(p10[k] & 0xffff0000u);
        float d0 = __uint_as_float(p11[k] << 16);
        float d1 = __uint_as_float(p11[k] & 0xffff0000u);
        acc[2 * k] += w00 * a0 + w01 * b0 + w10 * c0 + w11 * d0;
        acc[2 * k + 1] += w00 * a1 + w01 * b1 + w10 * c1 + w11 * d1;
      }
    }
  }
  float4* op = (float4*)(outs + (size_t)i * 256 + choff);
  op[0] = make_float4(acc[0], acc[1], acc[2], acc[3]);
  op[1] = make_float4(acc[4], acc[5], acc[6], acc[7]);
}

extern "C" void kernel_launch(void* const* d_in, const int* in_sizes, int n_in,
                              void* d_out, int out_size, void* d_ws, size_t ws_size,
                              hipStream_t stream) {
  const float* query  = (const float*)d_in[0];
  const float* bbox   = (const float*)d_in[1];
  const float* value  = (const float*)d_in[2];
  const float* W_off  = (const float*)d_in[3];
  const float* b_off  = (const float*)d_in[4];
  const float* W_attn = (const float*)d_in[5];
  const float* b_attn = (const float*)d_in[6];
  const float* W_val  = (const float*)d_in[7];
  const float* b_val  = (const float*)d_in[8];
  const float* W_out  = (const float*)d_in[9];
  const float* b_out  = (const float*)d_in[10];
  float* out = (float*)d_out;

  // workspace layout
  char* w = (char*)d_ws;
  u16* vbf     = (u16*)w;                          // 69,632,000 B
  float* offl  = (float*)(w + 69632000);           // 16,384,000 B (reused as outs)
  float* attnl = (float*)(w + 86016000);           //  8,192,000 B (reused as attnw)
  float* locs  = (float*)(w + 94208000);           // 16,384,000 B
  u16* Wt_val  = (u16*)(w + 110592000);            //    131,072 B
  u16* Wt_off  = (u16*)(w + 110723072);            //    131,072 B
  u16* Wt_attn = (u16*)(w + 110854144);            //     65,536 B
  u16* Wt_out  = (u16*)(w + 110919680);            //    131,072 B
  float* outs = offl;
  float* attnw = attnl;

  const int M_v = 16 * 8500;  // 136000
  const int M_q = 16 * 1000;  // 16000

  // 0) weight prep (bf16 transpose)
  wconv<<<dim3(4, 4, 4), 256, 0, stream>>>(W_val, W_off, W_attn, W_out,
                                           Wt_val, Wt_off, Wt_attn, Wt_out);
  // 1) value projection -> bf16
  gemm_bf16<true><<<dim3((M_v + 127) / 128, 2), 256, 0, stream>>>(
      value, Wt_val, b_val, (void*)vbf, M_v, 256);
  // 2) offset logits
  gemm_bf16<false><<<dim3(M_q / 128, 2), 256, 0, stream>>>(
      query, Wt_off, b_off, (void*)offl, M_q, 256);
  // 3) attn logits
  gemm_bf16<false><<<dim3(M_q / 128, 1), 256, 0, stream>>>(
      query, Wt_attn, b_attn, (void*)attnl, M_q, 128);
  // 4) softmax + locations
  qpost<<<M_q, 256, 0, stream>>>(offl, attnl, bbox, locs, attnw);
  // 5) bilinear sampling (writes outs == offl)
  sample<<<2000, 256, 0, stream>>>(locs, attnw, vbf, outs);
  // 6) output projection
  gemm_bf16<false><<<dim3(M_q / 128, 2), 256, 0, stream>>>(
      outs, Wt_out, b_out, (void*)out, M_q, 256);
}

// Round 4
// 180.570 us; speedup vs baseline: 3.4134x; 1.3535x over previous
//
#include <hip/hip_runtime.h>
#include <cstdint>
#include <cstddef>

// DeformablePoseViT: bs=16, lq=1000, d=256, nh=8, L=4, P=4, dh=32
// value pyramid: (80,80),(40,40),(20,20),(10,10) -> lv=8500
//
// Pipeline:
//  0) wconv      : Wt_* = bf16(W_*^T) [N][256]; Wt_qkv = concat(W_off,W_attn)
//  1) gemm_glds<true>  : vbf = bf16(value @ W_val + b_val)   [136000x256]
//  2) gemm_glds<false> : L   = query @ [W_off|W_attn] + b    [16000x384]
//  3) qpost      : softmax(L[:,256:384]) -> attnw, L[:,0:256] -> pixel locs
//  4) sample     : bilinear gather + attn-weighted sum -> outs (aliases L)
//  5) gemm_glds<false> : d_out = outs @ W_out + b_out        [16000x256]

typedef unsigned short u16;
typedef u16 u16x8 __attribute__((ext_vector_type(8)));
typedef __bf16 bf16x8 __attribute__((ext_vector_type(8)));
typedef float f32x4 __attribute__((ext_vector_type(4)));

__device__ inline u16 f2bf(float f) {
  return __builtin_bit_cast(u16, (__bf16)f);
}

__device__ __forceinline__ void glds16(const void* g, void* l) {
  __builtin_amdgcn_global_load_lds(
      (const __attribute__((address_space(1))) void*)g,
      (__attribute__((address_space(3))) void*)l, 16, 0, 0);
}

// ---------------------------------------------------------------------------
// Weight prep: Wt[n][k] = bf16(W[k][n]). K=256 for all 4 matrices.
// grid (4,4,4): x->n-tile, y->k-tile, z->matrix. Also builds combined bias.
__global__ __launch_bounds__(256) void wconv(
    const float* __restrict__ W0, const float* __restrict__ W1,
    const float* __restrict__ W2, const float* __restrict__ W3,
    u16* __restrict__ T0, u16* __restrict__ T1, u16* __restrict__ T2,
    u16* __restrict__ T3, const float* __restrict__ b_off,
    const float* __restrict__ b_attn, float* __restrict__ cbias) {
  __shared__ u16 tile[64][65];
  const float* Ws[4] = {W0, W1, W2, W3};
  u16* Ts[4] = {T0, T1, T2, T3};
  const int Ns[4] = {256, 256, 128, 256};
  const int z = blockIdx.z;
  const int N = Ns[z];
  const int n0 = blockIdx.x * 64;
  if (blockIdx.x == 0 && blockIdx.y == 0) {
    if (z == 1) cbias[threadIdx.x] = b_off[threadIdx.x];
    if (z == 2 && threadIdx.x < 128) cbias[256 + threadIdx.x] = b_attn[threadIdx.x];
  }
  if (n0 >= N) return;
  const int k0 = blockIdx.y * 64;
  const float* W = Ws[z];
  u16* Wt = Ts[z];
  const int tr = threadIdx.x >> 6;   // 0..3
  const int tc = threadIdx.x & 63;
#pragma unroll
  for (int r = 0; r < 64; r += 4)
    tile[r + tr][tc] = f2bf(W[(size_t)(k0 + r + tr) * N + n0 + tc]);
  __syncthreads();
#pragma unroll
  for (int r = 0; r < 64; r += 4)
    Wt[(size_t)(n0 + r + tr) * 256 + k0 + tc] = tile[tc][r + tr];
}

// ---------------------------------------------------------------------------
// C[M,N] = A[M,256]f32 (cast bf16) @ Wt[N,256]bf16^T + bias[N]
// BM=BN=128, BK=64, 256 threads = 4 waves 2x2, wave tile 64x64 (4x4 frags).
// Staging via async global_load_lds (width 16). A kept f32 in LDS (32KB),
// converted bf16 at fragment read. Swizzle: linear LDS dest + pre-swizzled
// global source + swizzled read (16B-granular XOR with row&7).
template <bool OUT_BF16>
__global__ __launch_bounds__(256) void gemm_glds(
    const float* __restrict__ A, const u16* __restrict__ Wt,
    const float* __restrict__ bias, void* __restrict__ Cv, int M, int N) {
  __shared__ __align__(16) float Asub[128 * 64];  // [row][k] f32, swizzled
  __shared__ __align__(16) u16 Bsub[128 * 64];    // [col][k] bf16, swizzled
  const int t = threadIdx.x;
  const int m0 = blockIdx.x * 128;
  const int n0 = blockIdx.y * 128;
  const int wave = t >> 6;
  const int lane = t & 63;
  const int wm = (wave >> 1) * 64;
  const int wn = (wave & 1) * 64;
  const int lr = lane & 15;
  const int kof = (lane >> 4) * 8;

  const int asub_r = lane >> 4;  // 0..3 (row within 4-row inst)
  const int achunk = lane & 15;  // 16B chunk within 256B row window
  const int bsub_c = lane >> 3;  // 0..7 (col within 8-col inst)
  const int bchunk = lane & 7;   // 16B chunk within 128B col window

  f32x4 acc[4][4] = {};

#pragma unroll
  for (int k0 = 0; k0 < 256; k0 += 64) {
    // stage A: 8 insts/wave x (4 rows x 64 f32)
#pragma unroll
    for (int g = 0; g < 8; ++g) {
      int row = g * 16 + wave * 4 + asub_r;
      int gr = m0 + row;
      if (gr > M - 1) gr = M - 1;  // clamp tail (no predication on glds)
      int sb = (achunk * 16) ^ ((row & 7) << 4);
      glds16((const char*)(A + (size_t)gr * 256 + k0) + sb,
             (char*)Asub + (g * 16 + wave * 4) * 256);
    }
    // stage B: 4 insts/wave x (8 cols x 64 bf16)
#pragma unroll
    for (int g = 0; g < 4; ++g) {
      int col = g * 32 + wave * 8 + bsub_c;
      int sb = (bchunk * 16) ^ ((col & 7) << 4);
      glds16((const char*)(Wt + (size_t)(n0 + col) * 256 + k0) + sb,
             (char*)Bsub + (g * 32 + wave * 8) * 128);
    }
    __syncthreads();  // drains vmcnt (compiler emits s_waitcnt before barrier)
#pragma unroll
    for (int kk = 0; kk < 64; kk += 32) {
      bf16x8 af[4], bfr[4];
#pragma unroll
      for (int mi = 0; mi < 4; ++mi) {
        int row = wm + mi * 16 + lr;
        int kb = (kk + kof) * 4;
        int sw = (row & 7) << 4;
        f32x4 a0 = *(const f32x4*)((const char*)Asub + row * 256 + (kb ^ sw));
        f32x4 a1 = *(const f32x4*)((const char*)Asub + row * 256 + ((kb + 16) ^ sw));
        bf16x8 v;
        v[0] = (__bf16)a0[0]; v[1] = (__bf16)a0[1];
        v[2] = (__bf16)a0[2]; v[3] = (__bf16)a0[3];
        v[4] = (__bf16)a1[0]; v[5] = (__bf16)a1[1];
        v[6] = (__bf16)a1[2]; v[7] = (__bf16)a1[3];
        af[mi] = v;
      }
#pragma unroll
      for (int ni = 0; ni < 4; ++ni) {
        int row = wn + ni * 16 + lr;
        int kb = (kk + kof) * 2;
        int byteoff = row * 128 + (kb ^ ((row & 7) << 4));
        bfr[ni] = __builtin_bit_cast(
            bf16x8, *(const u16x8*)((const char*)Bsub + byteoff));
      }
#pragma unroll
      for (int mi = 0; mi < 4; ++mi)
#pragma unroll
        for (int ni = 0; ni < 4; ++ni)
          acc[mi][ni] = __builtin_amdgcn_mfma_f32_16x16x32_bf16(
              af[mi], bfr[ni], acc[mi][ni], 0, 0, 0);
    }
    __syncthreads();
  }

  // epilogue: C layout col=lane&15, row=(lane>>4)*4+r
  float bv[4];
#pragma unroll
  for (int ni = 0; ni < 4; ++ni) bv[ni] = bias[n0 + wn + ni * 16 + lr];
  const int rit = (lane >> 4) * 4;
#pragma unroll
  for (int mi = 0; mi < 4; ++mi) {
#pragma unroll
    for (int r = 0; r < 4; ++r) {
      int grow = m0 + wm + mi * 16 + rit + r;
      if (grow >= M) continue;
#pragma unroll
      for (int ni = 0; ni < 4; ++ni) {
        int gcol = n0 + wn + ni * 16 + lr;
        float v = acc[mi][ni][r] + bv[ni];
        if (OUT_BF16)
          ((u16*)Cv)[(size_t)grow * N + gcol] = f2bf(v);
        else
          ((float*)Cv)[(size_t)grow * N + gcol] = v;
      }
    }
  }
}

// softmax over L*P=16 per head + pixel-space sampling locations.
// Reads combined logits Lg[16000][384]: cols 0-255 offsets, 256-383 attn.
__global__ __launch_bounds__(256) void qpost(
    const float* __restrict__ Lg, const float* __restrict__ bbox,
    float* __restrict__ locs, float* __restrict__ attnw) {
  const int i = blockIdx.x;
  const int t = threadIdx.x;
  __shared__ float sal[128];
  if (t < 128) sal[t] = Lg[(size_t)i * 384 + 256 + t];
  __syncthreads();
  if (t < 128) {
    int h = t >> 4;
    float mx = -3.0e38f;
#pragma unroll
    for (int j = 0; j < 16; ++j) mx = fmaxf(mx, sal[h * 16 + j]);
    float sum = 0.f;
#pragma unroll
    for (int j = 0; j < 16; ++j) sum += __expf(sal[h * 16 + j] - mx);
    attnw[(size_t)i * 128 + t] = __expf(sal[t] - mx) / sum;
  }
  int r = t & 31;
  int l = r >> 3;
  int xy = r & 1;
  float off = Lg[(size_t)i * 384 + t];
  float c = bbox[(size_t)i * 4 + xy];
  float wh = bbox[(size_t)i * 4 + 2 + xy];
  float loc = c + off * 0.125f * wh;  // off/P * wh * 0.5
  float size = (float)(80 >> l);      // 80,40,20,10
  locs[(size_t)i * 256 + t] = loc * size - 0.5f;
}

// ---------------------------------------------------------------------------
// bilinear sampling: 8 queries/block, 256 threads = ql*32 + (h*4 + cg)
__global__ __launch_bounds__(256) void sample(
    const float* __restrict__ locs, const float* __restrict__ attnw,
    const u16* __restrict__ vbf, float* __restrict__ outs) {
  const int blk = blockIdx.x;
  const int i0 = blk * 8;
  const int t = threadIdx.x;
  __shared__ __align__(16) float sl[8 * 256];
  __shared__ __align__(16) float sa[8 * 128];
  {
    const float4* src = (const float4*)(locs + (size_t)i0 * 256);
    float4* dst = (float4*)sl;
    dst[t] = src[t];
    dst[t + 256] = src[t + 256];
    ((float4*)sa)[t] = ((const float4*)(attnw + (size_t)i0 * 128))[t];
  }
  __syncthreads();
  const int ql = t >> 5;
  const int r = t & 31;
  const int h = r >> 2;
  const int cg = r & 3;
  const int choff = h * 32 + cg * 8;
  const int i = i0 + ql;
  const int b = blk / 125;
  const u16* vb = vbf + (size_t)b * 8500 * 256;

  float acc[8] = {};
  const int baseL[4] = {0, 6400, 8000, 8400};
  const int dimL[4] = {80, 40, 20, 10};

#pragma unroll
  for (int l = 0; l < 4; ++l) {
    const int W = dimL[l];
    const u16* vl = vb + (size_t)baseL[l] * 256 + choff;
#pragma unroll
    for (int p = 0; p < 4; ++p) {
      float x = sl[ql * 256 + h * 32 + l * 8 + p * 2 + 0];
      float y = sl[ql * 256 + h * 32 + l * 8 + p * 2 + 1];
      float aw = sa[ql * 128 + h * 16 + l * 4 + p];
      float x0f = floorf(x), y0f = floorf(y);
      float wx = x - x0f, wy = y - y0f;
      int x0 = (int)x0f, y0 = (int)y0f;
      int x1 = x0 + 1, y1 = y0 + 1;
      float fx0 = (x0 >= 0 && x0 < W) ? 1.f : 0.f;
      float fx1 = (x1 >= 0 && x1 < W) ? 1.f : 0.f;
      float fy0 = (y0 >= 0 && y0 < W) ? 1.f : 0.f;
      float fy1 = (y1 >= 0 && y1 < W) ? 1.f : 0.f;
      int xc0 = min(max(x0, 0), W - 1), xc1 = min(max(x1, 0), W - 1);
      int yc0 = min(max(y0, 0), W - 1), yc1 = min(max(y1, 0), W - 1);
      float w00 = aw * (1.f - wx) * (1.f - wy) * fx0 * fy0;
      float w01 = aw * wx * (1.f - wy) * fx1 * fy0;
      float w10 = aw * (1.f - wx) * wy * fx0 * fy1;
      float w11 = aw * wx * wy * fx1 * fy1;
      uint4 v00 = *(const uint4*)(vl + (size_t)(yc0 * W + xc0) * 256);
      uint4 v01 = *(const uint4*)(vl + (size_t)(yc0 * W + xc1) * 256);
      uint4 v10 = *(const uint4*)(vl + (size_t)(yc1 * W + xc0) * 256);
      uint4 v11 = *(const uint4*)(vl + (size_t)(yc1 * W + xc1) * 256);
      const uint32_t* p00 = (const uint32_t*)&v00;
      const uint32_t* p01 = (const uint32_t*)&v01;
      const uint32_t* p10 = (const uint32_t*)&v10;
      const uint32_t* p11 = (const uint32_t*)&v11;
#pragma unroll
      for (int k = 0; k < 4; ++k) {
        float a0 = __uint_as_float(p00[k] << 16);
        float a1 = __uint_as_float(p00[k] & 0xffff0000u);
        float b0 = __uint_as_float(p01[k] << 16);
        float b1 = __uint_as_float(p01[k] & 0xffff0000u);
        float c0 = __uint_as_float(p10[k] << 16);
        float c1 = __uint_as_float(p10[k] & 0xffff0000u);
        float d0 = __uint_as_float(p11[k] << 16);
        float d1 = __uint_as_float(p11[k] & 0xffff0000u);
        acc[2 * k] += w00 * a0 + w01 * b0 + w10 * c0 + w11 * d0;
        acc[2 * k + 1] += w00 * a1 + w01 * b1 + w10 * c1 + w11 * d1;
      }
    }
  }
  float4* op = (float4*)(outs + (size_t)i * 256 + choff);
  op[0] = make_float4(acc[0], acc[1], acc[2], acc[3]);
  op[1] = make_float4(acc[4], acc[5], acc[6], acc[7]);
}

extern "C" void kernel_launch(void* const* d_in, const int* in_sizes, int n_in,
                              void* d_out, int out_size, void* d_ws, size_t ws_size,
                              hipStream_t stream) {
  const float* query  = (const float*)d_in[0];
  const float* bbox   = (const float*)d_in[1];
  const float* value  = (const float*)d_in[2];
  const float* W_off  = (const float*)d_in[3];
  const float* b_off  = (const float*)d_in[4];
  const float* W_attn = (const float*)d_in[5];
  const float* b_attn = (const float*)d_in[6];
  const float* W_val  = (const float*)d_in[7];
  const float* b_val  = (const float*)d_in[8];
  const float* W_out  = (const float*)d_in[9];
  const float* b_out  = (const float*)d_in[10];
  float* out = (float*)d_out;

  // workspace layout
  char* w = (char*)d_ws;
  u16* vbf     = (u16*)w;                    // 69,632,000 B
  float* Lg    = (float*)(w + 69632000);     // 16000*384*4 = 24,576,000 B
  float* attnw = (float*)(w + 94208000);     //  8,192,000 B
  float* locs  = (float*)(w + 102400000);    // 16,384,000 B
  u16* Wt_val  = (u16*)(w + 118784000);      //    131,072 B
  u16* Wt_qkv  = (u16*)(w + 118915072);      //    196,608 B (384x256)
  u16* Wt_out  = (u16*)(w + 119111680);      //    131,072 B
  float* cbias = (float*)(w + 119242752);    //      1,536 B
  float* outs  = Lg;  // alias: Lg fully consumed by qpost before sample writes

  const int M_v = 16 * 8500;  // 136000
  const int M_q = 16 * 1000;  // 16000

  // 0) weight prep (bf16 transpose + combined qkv weights/bias)
  wconv<<<dim3(4, 4, 4), 256, 0, stream>>>(
      W_val, W_off, W_attn, W_out, Wt_val, Wt_qkv, Wt_qkv + 256 * 256, Wt_out,
      b_off, b_attn, cbias);
  // 1) value projection -> bf16
  gemm_glds<true><<<dim3((M_v + 127) / 128, 2), 256, 0, stream>>>(
      value, Wt_val, b_val, (void*)vbf, M_v, 256);
  // 2) combined offset+attn logits [16000x384]
  gemm_glds<false><<<dim3(M_q / 128, 3), 256, 0, stream>>>(
      query, Wt_qkv, cbias, (void*)Lg, M_q, 384);
  // 3) softmax + locations
  qpost<<<M_q, 256, 0, stream>>>(Lg, bbox, locs, attnw);
  // 4) bilinear sampling (writes outs == Lg)
  sample<<<2000, 256, 0, stream>>>(locs, attnw, vbf, outs);
  // 5) output projection
  gemm_glds<false><<<dim3(M_q / 128, 2), 256, 0, stream>>>(
      outs, Wt_out, b_out, (void*)out, M_q, 256);
}

// Round 5
// 169.976 us; speedup vs baseline: 3.6262x; 1.0623x over previous
//
#include <hip/hip_runtime.h>
#include <cstdint>
#include <cstddef>

// DeformablePoseViT: bs=16, lq=1000, d=256, nh=8, L=4, P=4, dh=32
// value pyramid: (80,80),(40,40),(20,20),(10,10) -> lv=8500
//
// Pipeline:
//  0) wconv         : Wt_* = bf16(W_*^T) [N][256]; Wt_qkv = [W_off|W_attn]
//  1) gemm_db<true> : vbf = bf16(value @ W_val + b_val)   [136000x256]
//  2) gemm_db<false>: Lg  = query @ [W_off|W_attn] + b    [16000x384]
//  3) sample_fused  : softmax+locs (in-block) + bilinear gather -> outs
//  4) gemm_db<false>: d_out = outs @ W_out + b_out        [16000x256]
//
// gemm_db: BM=BN=128, BK=32, ping-pong LDS double-buffer staged via
// global_load_lds(16B) with counted s_waitcnt vmcnt(6) (T3/T4 pattern:
// next-tile loads stay in flight across the barrier; never drain to 0
// in the main loop).

typedef unsigned short u16;
typedef u16 u16x8 __attribute__((ext_vector_type(8)));
typedef __bf16 bf16x8 __attribute__((ext_vector_type(8)));
typedef float f32x4 __attribute__((ext_vector_type(4)));

__device__ inline u16 f2bf(float f) {
  return __builtin_bit_cast(u16, (__bf16)f);
}

__device__ __forceinline__ void glds16(const void* g, void* l) {
  __builtin_amdgcn_global_load_lds(
      (const __attribute__((address_space(1))) void*)g,
      (__attribute__((address_space(3))) void*)l, 16, 0, 0);
}

// ---------------------------------------------------------------------------
// Weight prep: Wt[n][k] = bf16(W[k][n]). K=256 for all 4 matrices.
// grid (4,4,4): x->n-tile, y->k-tile, z->matrix. Also builds combined bias.
__global__ __launch_bounds__(256) void wconv(
    const float* __restrict__ W0, const float* __restrict__ W1,
    const float* __restrict__ W2, const float* __restrict__ W3,
    u16* __restrict__ T0, u16* __restrict__ T1, u16* __restrict__ T2,
    u16* __restrict__ T3, const float* __restrict__ b_off,
    const float* __restrict__ b_attn, float* __restrict__ cbias) {
  __shared__ u16 tile[64][65];
  const float* Ws[4] = {W0, W1, W2, W3};
  u16* Ts[4] = {T0, T1, T2, T3};
  const int Ns[4] = {256, 256, 128, 256};
  const int z = blockIdx.z;
  const int N = Ns[z];
  const int n0 = blockIdx.x * 64;
  if (blockIdx.x == 0 && blockIdx.y == 0) {
    if (z == 1) cbias[threadIdx.x] = b_off[threadIdx.x];
    if (z == 2 && threadIdx.x < 128) cbias[256 + threadIdx.x] = b_attn[threadIdx.x];
  }
  if (n0 >= N) return;
  const int k0 = blockIdx.y * 64;
  const float* W = Ws[z];
  u16* Wt = Ts[z];
  const int tr = threadIdx.x >> 6;   // 0..3
  const int tc = threadIdx.x & 63;
#pragma unroll
  for (int r = 0; r < 64; r += 4)
    tile[r + tr][tc] = f2bf(W[(size_t)(k0 + r + tr) * N + n0 + tc]);
  __syncthreads();
#pragma unroll
  for (int r = 0; r < 64; r += 4)
    Wt[(size_t)(n0 + r + tr) * 256 + k0 + tc] = tile[tc][r + tr];
}

// ---------------------------------------------------------------------------
// C[M,N] = A[M,256]f32 (cast bf16) @ Wt[N,256]bf16^T + bias[N]
// 256 threads = 4 waves 2x2, wave tile 64x64 (4x4 16x16 frags).
// A kept f32 in LDS (16KB/buf), B bf16 (8KB/buf); 2 buffers = 48KB.
// Swizzle: linear LDS dest + pre-swizzled global source + swizzled read.
template <bool OUT_BF16>
__global__ __launch_bounds__(256) void gemm_db(
    const float* __restrict__ A, const u16* __restrict__ Wt,
    const float* __restrict__ bias, void* __restrict__ Cv, int M, int N) {
  __shared__ __align__(16) float Asub[2][128 * 32];  // [row][k] f32, swizzled
  __shared__ __align__(16) u16 Bsub[2][128 * 32];    // [col][k] bf16, swizzled
  const int t = threadIdx.x;
  const int m0 = blockIdx.x * 128;
  const int n0 = blockIdx.y * 128;
  const int wave = t >> 6;
  const int lane = t & 63;
  const int wm = (wave >> 1) * 64;
  const int wn = (wave & 1) * 64;
  const int lr = lane & 15;
  const int kof = (lane >> 4) * 8;  // k-element offset of this lane's frag

  // staging geometry (per-lane pre-swizzled global source)
  const int a_sub = lane >> 3;              // row within 8-row inst; == ldsrow&7
  const int a_chunk = (lane & 7) ^ a_sub;   // 16B chunk, XOR-swizzled
  const int b_sub = lane >> 2;              // col within 16-col inst
  const int b_chunk = (lane & 3) ^ (b_sub & 3);

  f32x4 acc[4][4] = {};

  auto stageA = [&](float* buf, int k0) {
#pragma unroll
    for (int g = 0; g < 4; ++g) {
      int row = wave * 32 + g * 8 + a_sub;
      int gr = m0 + row;
      if (gr > M - 1) gr = M - 1;  // clamp tail (no predication on glds)
      glds16((const char*)A + (size_t)gr * 1024 + k0 * 4 + a_chunk * 16,
             (char*)buf + (wave * 32 + g * 8) * 128);
    }
  };
  auto stageB = [&](u16* buf, int k0) {
#pragma unroll
    for (int g = 0; g < 2; ++g) {
      int col = (wave * 2 + g) * 16 + b_sub;
      glds16((const char*)Wt + (size_t)(n0 + col) * 512 + k0 * 2 + b_chunk * 16,
             (char*)buf + (wave * 2 + g) * 1024);
    }
  };
  auto compute = [&](const float* bufA, const u16* bufB) {
    bf16x8 af[4], bfr[4];
#pragma unroll
    for (int mi = 0; mi < 4; ++mi) {
      int row = wm + mi * 16 + lr;
      int sw = row & 7;
      int c0 = kof >> 2;  // 0,2,4,6
      f32x4 a0 = *(const f32x4*)((const char*)bufA + row * 128 + ((c0 ^ sw) * 16));
      f32x4 a1 = *(const f32x4*)((const char*)bufA + row * 128 + (((c0 + 1) ^ sw) * 16));
      bf16x8 v;
      v[0] = (__bf16)a0[0]; v[1] = (__bf16)a0[1];
      v[2] = (__bf16)a0[2]; v[3] = (__bf16)a0[3];
      v[4] = (__bf16)a1[0]; v[5] = (__bf16)a1[1];
      v[6] = (__bf16)a1[2]; v[7] = (__bf16)a1[3];
      af[mi] = v;
    }
#pragma unroll
    for (int ni = 0; ni < 4; ++ni) {
      int col = wn + ni * 16 + lr;
      int chunk = (kof >> 3) ^ (col & 3);
      bfr[ni] = __builtin_bit_cast(
          bf16x8, *(const u16x8*)((const char*)bufB + col * 64 + chunk * 16));
    }
#pragma unroll
    for (int mi = 0; mi < 4; ++mi)
#pragma unroll
      for (int ni = 0; ni < 4; ++ni)
        acc[mi][ni] = __builtin_amdgcn_mfma_f32_16x16x32_bf16(
            af[mi], bfr[ni], acc[mi][ni], 0, 0, 0);
  };

  // prologue: stage tile 0
  stageA(Asub[0], 0);
  stageB(Bsub[0], 0);
#pragma unroll
  for (int tk = 0; tk < 8; ++tk) {
    const int p = tk & 1;
    if (tk < 7) {
      stageA(Asub[p ^ 1], (tk + 1) * 32);
      stageB(Bsub[p ^ 1], (tk + 1) * 32);
      asm volatile("s_waitcnt vmcnt(6)" ::: "memory");  // tile-tk loads done
    } else {
      asm volatile("s_waitcnt vmcnt(0)" ::: "memory");
    }
    __builtin_amdgcn_s_barrier();
    compute(Asub[p], Bsub[p]);
    __builtin_amdgcn_s_barrier();
  }

  // epilogue: C layout col=lane&15, row=(lane>>4)*4+r
  float bv[4];
#pragma unroll
  for (int ni = 0; ni < 4; ++ni) bv[ni] = bias[n0 + wn + ni * 16 + lr];
  const int rit = (lane >> 4) * 4;
#pragma unroll
  for (int mi = 0; mi < 4; ++mi) {
#pragma unroll
    for (int r = 0; r < 4; ++r) {
      int grow = m0 + wm + mi * 16 + rit + r;
      if (grow >= M) continue;
#pragma unroll
      for (int ni = 0; ni < 4; ++ni) {
        int gcol = n0 + wn + ni * 16 + lr;
        float v = acc[mi][ni][r] + bv[ni];
        if (OUT_BF16)
          ((u16*)Cv)[(size_t)grow * N + gcol] = f2bf(v);
        else
          ((float*)Cv)[(size_t)grow * N + gcol] = v;
      }
    }
  }
}

// ---------------------------------------------------------------------------
// Fused qpost+sample: 8 queries/block. Phase 1: stage bbox + attn logits.
// Phase 2: compute pixel locs (sl) + softmax (sa). Phase 3: bilinear gather.
// 256 threads in gather = ql*32 + (h*4 + cg).
__global__ __launch_bounds__(256) void sample_fused(
    const float* __restrict__ Lg, const float* __restrict__ bbox,
    const u16* __restrict__ vbf, float* __restrict__ outs) {
  const int blk = blockIdx.x;
  const int i0 = blk * 8;
  const int t = threadIdx.x;
  __shared__ __align__(16) float sl[8 * 256];
  __shared__ __align__(16) float sa[8 * 128];
  __shared__ float sb[32];
  if (t < 32) sb[t] = bbox[(size_t)i0 * 4 + t];
#pragma unroll
  for (int j = 0; j < 4; ++j) {
    int idx = j * 256 + t;
    int ql = idx >> 7, c = idx & 127;
    sa[idx] = Lg[(size_t)(i0 + ql) * 384 + 256 + c];
  }
  __syncthreads();
  // pixel-space locations from offset logits
#pragma unroll
  for (int j = 0; j < 8; ++j) {
    int idx = j * 256 + t;
    int ql = idx >> 8, e = idx & 255;
    float off = Lg[(size_t)(i0 + ql) * 384 + e];
    int l = (e >> 3) & 3, xy = e & 1;
    float c = sb[ql * 4 + xy], wh = sb[ql * 4 + 2 + xy];
    sl[idx] = (c + off * 0.125f * wh) * (float)(80 >> l) - 0.5f;
  }
  // softmax over 16 per (query, head): threads 0..63
  if (t < 64) {
    int base = (t >> 3) * 128 + (t & 7) * 16;
    float mx = -3.0e38f;
#pragma unroll
    for (int j = 0; j < 16; ++j) mx = fmaxf(mx, sa[base + j]);
    float e[16];
    float s = 0.f;
#pragma unroll
    for (int j = 0; j < 16; ++j) {
      e[j] = __expf(sa[base + j] - mx);
      s += e[j];
    }
    float inv = 1.f / s;
#pragma unroll
    for (int j = 0; j < 16; ++j) sa[base + j] = e[j] * inv;
  }
  __syncthreads();

  const int ql = t >> 5;
  const int r = t & 31;
  const int h = r >> 2;
  const int cg = r & 3;
  const int choff = h * 32 + cg * 8;
  const int i = i0 + ql;
  const int b = blk / 125;
  const u16* vb = vbf + (size_t)b * 8500 * 256;

  float acc[8] = {};
  const int baseL[4] = {0, 6400, 8000, 8400};
  const int dimL[4] = {80, 40, 20, 10};

#pragma unroll
  for (int l = 0; l < 4; ++l) {
    const int W = dimL[l];
    const u16* vl = vb + (size_t)baseL[l] * 256 + choff;
#pragma unroll
    for (int p = 0; p < 4; ++p) {
      float x = sl[ql * 256 + h * 32 + l * 8 + p * 2 + 0];
      float y = sl[ql * 256 + h * 32 + l * 8 + p * 2 + 1];
      float aw = sa[ql * 128 + h * 16 + l * 4 + p];
      float x0f = floorf(x), y0f = floorf(y);
      float wx = x - x0f, wy = y - y0f;
      int x0 = (int)x0f, y0 = (int)y0f;
      int x1 = x0 + 1, y1 = y0 + 1;
      float fx0 = (x0 >= 0 && x0 < W) ? 1.f : 0.f;
      float fx1 = (x1 >= 0 && x1 < W) ? 1.f : 0.f;
      float fy0 = (y0 >= 0 && y0 < W) ? 1.f : 0.f;
      float fy1 = (y1 >= 0 && y1 < W) ? 1.f : 0.f;
      int xc0 = min(max(x0, 0), W - 1), xc1 = min(max(x1, 0), W - 1);
      int yc0 = min(max(y0, 0), W - 1), yc1 = min(max(y1, 0), W - 1);
      float w00 = aw * (1.f - wx) * (1.f - wy) * fx0 * fy0;
      float w01 = aw * wx * (1.f - wy) * fx1 * fy0;
      float w10 = aw * (1.f - wx) * wy * fx0 * fy1;
      float w11 = aw * wx * wy * fx1 * fy1;
      uint4 v00 = *(const uint4*)(vl + (size_t)(yc0 * W + xc0) * 256);
      uint4 v01 = *(const uint4*)(vl + (size_t)(yc0 * W + xc1) * 256);
      uint4 v10 = *(const uint4*)(vl + (size_t)(yc1 * W + xc0) * 256);
      uint4 v11 = *(const uint4*)(vl + (size_t)(yc1 * W + xc1) * 256);
      const uint32_t* p00 = (const uint32_t*)&v00;
      const uint32_t* p01 = (const uint32_t*)&v01;
      const uint32_t* p10 = (const uint32_t*)&v10;
      const uint32_t* p11 = (const uint32_t*)&v11;
#pragma unroll
      for (int k = 0; k < 4; ++k) {
        float a0 = __uint_as_float(p00[k] << 16);
        float a1 = __uint_as_float(p00[k] & 0xffff0000u);
        float b0 = __uint_as_float(p01[k] << 16);
        float b1 = __uint_as_float(p01[k] & 0xffff0000u);
        float c0 = __uint_as_float(p10[k] << 16);
        float c1 = __uint_as_float(p10[k] & 0xffff0000u);
        float d0 = __uint_as_float(p11[k] << 16);
        float d1 = __uint_as_float(p11[k] & 0xffff0000u);
        acc[2 * k] += w00 * a0 + w01 * b0 + w10 * c0 + w11 * d0;
        acc[2 * k + 1] += w00 * a1 + w01 * b1 + w10 * c1 + w11 * d1;
      }
    }
  }
  float4* op = (float4*)(outs + (size_t)i * 256 + choff);
  op[0] = make_float4(acc[0], acc[1], acc[2], acc[3]);
  op[1] = make_float4(acc[4], acc[5], acc[6], acc[7]);
}

extern "C" void kernel_launch(void* const* d_in, const int* in_sizes, int n_in,
                              void* d_out, int out_size, void* d_ws, size_t ws_size,
                              hipStream_t stream) {
  const float* query  = (const float*)d_in[0];
  const float* bbox   = (const float*)d_in[1];
  const float* value  = (const float*)d_in[2];
  const float* W_off  = (const float*)d_in[3];
  const float* b_off  = (const float*)d_in[4];
  const float* W_attn = (const float*)d_in[5];
  const float* b_attn = (const float*)d_in[6];
  const float* W_val  = (const float*)d_in[7];
  const float* b_val  = (const float*)d_in[8];
  const float* W_out  = (const float*)d_in[9];
  const float* b_out  = (const float*)d_in[10];
  float* out = (float*)d_out;

  // workspace layout
  char* w = (char*)d_ws;
  u16* vbf     = (u16*)w;                    // 69,632,000 B
  float* Lg    = (float*)(w + 69632000);     // 16000*384*4 = 24,576,000 B
  float* outs  = (float*)(w + 94208000);     // 16000*256*4 = 16,384,000 B
  u16* Wt_val  = (u16*)(w + 110592000);      //    131,072 B
  u16* Wt_qkv  = (u16*)(w + 110723072);      //    196,608 B (384x256)
  u16* Wt_out  = (u16*)(w + 110919680);      //    131,072 B
  float* cbias = (float*)(w + 111050752);    //      1,536 B

  const int M_v = 16 * 8500;  // 136000
  const int M_q = 16 * 1000;  // 16000

  // 0) weight prep (bf16 transpose + combined qkv weights/bias)
  wconv<<<dim3(4, 4, 4), 256, 0, stream>>>(
      W_val, W_off, W_attn, W_out, Wt_val, Wt_qkv, Wt_qkv + 256 * 256, Wt_out,
      b_off, b_attn, cbias);
  // 1) value projection -> bf16
  gemm_db<true><<<dim3((M_v + 127) / 128, 2), 256, 0, stream>>>(
      value, Wt_val, b_val, (void*)vbf, M_v, 256);
  // 2) combined offset+attn logits [16000x384]
  gemm_db<false><<<dim3(M_q / 128, 3), 256, 0, stream>>>(
      query, Wt_qkv, cbias, (void*)Lg, M_q, 384);
  // 3) fused softmax/locs + bilinear sampling
  sample_fused<<<2000, 256, 0, stream>>>(Lg, bbox, vbf, outs);
  // 4) output projection
  gemm_db<false><<<dim3(M_q / 128, 2), 256, 0, stream>>>(
      outs, Wt_out, b_out, (void*)out, M_q, 256);
}